// Round 3
// baseline (2301.645 us; speedup 1.0000x reference)
//
#include <hip/hip_runtime.h>

#define TT 512
#define BB 1024
#define XD 24
#define ZD 16

typedef __attribute__((ext_vector_type(4))) _Float16 half4;
typedef __attribute__((ext_vector_type(4))) float f32x4;

__device__ __forceinline__ f32x4 MFMA16(half4 a, half4 b, f32x4 c) {
#if defined(__HIP_DEVICE_COMPILE__)
    return __builtin_amdgcn_mfma_f32_16x16x16f16(a, b, c, 0, 0, 0);
#else
    return c;   // host pass never executes device code; keep the parser happy
#endif
}

__device__ __forceinline__ float sigm(float x) { return 1.0f / (1.0f + __expf(-x)); }

__device__ __forceinline__ float tanh_fast(float x) {
    x = fminf(fmaxf(x, -30.0f), 30.0f);
    float e = __expf(2.0f * x);
    return (e - 1.0f) / (e + 1.0f);
}

__device__ __forceinline__ float softplus_f(float x) {
    return fmaxf(x, 0.0f) + log1pf(__expf(-fabsf(x)));
}

// A-fragment of W^T (16 out-feats x 16 k) for 16x16x16 f16 MFMA.
// Lane l holds WT[o0 + (l&15)][k0 + (l>>4)*4 + j] = W[k0+(l>>4)*4+j][o0+(l&15)],
// zero-padded outside Kreal/Nreal. W is row-major [K][N].
__device__ __forceinline__ half4 ldw(const float* W, int N, int Kreal, int Nreal,
                                     int k0, int o0, int lane) {
    int col = o0 + (lane & 15);
    int kb = k0 + ((lane >> 4) << 2);
    half4 r;
#pragma unroll
    for (int j = 0; j < 4; ++j) {
        int k = kb + j;
        float v = (k < Kreal && col < Nreal) ? W[(size_t)k * N + col] : 0.0f;
        r[j] = (_Float16)v;
    }
    return r;
}

__device__ __forceinline__ half4 cvt_relu(f32x4 a) {
    half4 r;
#pragma unroll
    for (int q = 0; q < 4; ++q) r[q] = (_Float16)fmaxf(a[q], 0.0f);
    return r;
}

__device__ __forceinline__ half4 cvt4(f32x4 a) {
    half4 r;
#pragma unroll
    for (int q = 0; q < 4; ++q) r[q] = (_Float16)a[q];
    return r;
}

// per-lane-group bias slice: bias values for D rows (lgr*4 .. lgr*4+3) of out-tile o
__device__ __forceinline__ f32x4 ldb4(const float* b, int o, int lgr) {
    return *reinterpret_cast<const f32x4*>(b + o * 16 + lgr * 4);
}

__device__ __forceinline__ unsigned long long h2u(half4 h) {
    union { half4 h; unsigned long long u; } c; c.h = h; return c.u;
}
__device__ __forceinline__ half4 u2h(unsigned long long u) {
    union { half4 h; unsigned long long u; } c; c.u = u; return c.h;
}

__global__ __launch_bounds__(128, 1) void vrnn_kernel(
    const float* __restrict__ src, const float* __restrict__ eps,
    const float* __restrict__ Wx1, const float* __restrict__ bx1,
    const float* __restrict__ Wx2, const float* __restrict__ bx2,
    const float* __restrict__ Wz,  const float* __restrict__ bz,
    const float* __restrict__ We1, const float* __restrict__ be1,
    const float* __restrict__ We2, const float* __restrict__ be2,
    const float* __restrict__ Wem, const float* __restrict__ bem,
    const float* __restrict__ Wes, const float* __restrict__ bes,
    const float* __restrict__ Wih, const float* __restrict__ Whh,
    const float* __restrict__ Wf1, const float* __restrict__ bf1,
    const float* __restrict__ Wf2, const float* __restrict__ bf2,
    const float* __restrict__ Wf3, const float* __restrict__ bf3,
    float* __restrict__ out)
{
    // Cross-wave exchange buffers (B-fragment form: one 8B word per lane per frag)
    __shared__ unsigned long long PHIB[8 * 64];  // frags 0-3: phi_x, 4-7: phi_z
    __shared__ unsigned long long HBUF[4 * 64];  // h (frags 0-3)

    const int tid = threadIdx.x;
    const int wid = tid >> 6;
    const int lane = tid & 63;
    const int lcol = lane & 15;   // batch column
    const int lgr = lane >> 4;    // lane group (k / D-row group)
    const int r0 = blockIdx.x * 16;

    if (wid == 0) {
        // ================= wave 0: phi_x / enc / z / phi_z chain =================
        half4 wx1[4][2], wx2[4][4], we1[4][8], we2[4][4], wem[4], wes[4], wzf[4];
#pragma unroll
        for (int o = 0; o < 4; ++o) {
            wx1[o][0] = ldw(Wx1, 64, 24, 64, 0, o * 16, lane);
            wx1[o][1] = ldw(Wx1, 64, 24, 64, 16, o * 16, lane);
#pragma unroll
            for (int kt = 0; kt < 4; ++kt) wx2[o][kt] = ldw(Wx2, 64, 64, 64, kt * 16, o * 16, lane);
#pragma unroll
            for (int kt = 0; kt < 8; ++kt) we1[o][kt] = ldw(We1, 64, 128, 64, kt * 16, o * 16, lane);
#pragma unroll
            for (int kt = 0; kt < 4; ++kt) we2[o][kt] = ldw(We2, 64, 64, 64, kt * 16, o * 16, lane);
            wzf[o] = ldw(Wz, 64, 16, 64, 0, o * 16, lane);
        }
#pragma unroll
        for (int kt = 0; kt < 4; ++kt) {
            wem[kt] = ldw(Wem, 16, 64, 16, kt * 16, 0, lane);
            wes[kt] = ldw(Wes, 16, 64, 16, kt * 16, 0, lane);
        }
        f32x4 B1[4], B2[4], BE1[4], BE2[4], BZ[4];
#pragma unroll
        for (int o = 0; o < 4; ++o) {
            B1[o] = ldb4(bx1, o, lgr);
            B2[o] = ldb4(bx2, o, lgr);
            BE1[o] = ldb4(be1, o, lgr);
            BE2[o] = ldb4(be2, o, lgr);
            BZ[o] = ldb4(bz, o, lgr);
        }
        f32x4 BM = ldb4(bem, 0, lgr), BS = ldb4(bes, 0, lgr);

        // x/eps prefetch (fragment-layout aligned float4 loads)
        const float* xb_ = src + (size_t)(r0 + lcol) * TT * XD;
        const float* eb_ = eps + (size_t)(r0 + lcol) * TT * ZD;
        f32x4 fx1 = (f32x4){0.f, 0.f, 0.f, 0.f};
        f32x4 fx0 = *reinterpret_cast<const f32x4*>(xb_ + lgr * 4);
        if (lgr < 2) fx1 = *reinterpret_cast<const f32x4*>(xb_ + 16 + lgr * 4);
        f32x4 fe = *reinterpret_cast<const f32x4*>(eb_ + lgr * 4);

        f32x4 pzlast[4];
        half4 pzb[4];

        __syncthreads();   // pre-loop (h=0 published by wave1)

#pragma unroll 1
        for (int t = 0; t < TT; ++t) {
            half4 xb0c = cvt4(fx0);
            half4 xb1c = cvt4(fx1);        // lanes lgr>=2 stay exactly 0 (k-padding)
            f32x4 eC = fe;
            if (t + 1 < TT) {
                fx0 = *reinterpret_cast<const f32x4*>(xb_ + (size_t)(t + 1) * XD + lgr * 4);
                if (lgr < 2) fx1 = *reinterpret_cast<const f32x4*>(xb_ + (size_t)(t + 1) * XD + 16 + lgr * 4);
                fe = *reinterpret_cast<const f32x4*>(eb_ + (size_t)(t + 1) * ZD + lgr * 4);
            }

            // s1: axT = relu(Wx1^T @ xT + bx1)
            half4 axb[4];
#pragma unroll
            for (int o = 0; o < 4; ++o) {
                f32x4 a = B1[o];
                a = MFMA16(wx1[o][0], xb0c, a);
                a = MFMA16(wx1[o][1], xb1c, a);
                axb[o] = cvt_relu(a);
            }
            // s2: phi_xT
            half4 pxb[4];
#pragma unroll
            for (int o = 0; o < 4; ++o) {
                f32x4 a = B2[o];
#pragma unroll
                for (int kt = 0; kt < 4; ++kt) a = MFMA16(wx2[o][kt], axb[kt], a);
                pxb[o] = cvt_relu(a);
            }

            __syncthreads();   // A: h(t-1) frags visible in HBUF

            half4 hb[4];
#pragma unroll
            for (int kt = 0; kt < 4; ++kt) hb[kt] = u2h(HBUF[kt * 64 + lane]);

            // s3: a1T = relu(We1^T @ [phi_x | h]T + be1)
            half4 a1b[4];
#pragma unroll
            for (int o = 0; o < 4; ++o) {
                f32x4 a = BE1[o];
#pragma unroll
                for (int kt = 0; kt < 4; ++kt) a = MFMA16(we1[o][kt], pxb[kt], a);
#pragma unroll
                for (int kt = 0; kt < 4; ++kt) a = MFMA16(we1[o][4 + kt], hb[kt], a);
                a1b[o] = cvt_relu(a);
            }
            // s4: encT
            half4 enb[4];
#pragma unroll
            for (int o = 0; o < 4; ++o) {
                f32x4 a = BE2[o];
#pragma unroll
                for (int kt = 0; kt < 4; ++kt) a = MFMA16(we2[o][kt], a1b[kt], a);
                enb[o] = cvt_relu(a);
            }
            // s5: mean/std -> z (D-layout, f32)
            f32x4 am = BM, as_ = BS;
#pragma unroll
            for (int kt = 0; kt < 4; ++kt) am = MFMA16(wem[kt], enb[kt], am);
#pragma unroll
            for (int kt = 0; kt < 4; ++kt) as_ = MFMA16(wes[kt], enb[kt], as_);
            f32x4 zD;
#pragma unroll
            for (int q = 0; q < 4; ++q) zD[q] = eC[q] * softplus_f(as_[q]) + am[q];
            half4 zb = cvt4(zD);

            // s6: phi_zT
#pragma unroll
            for (int o = 0; o < 4; ++o) {
                f32x4 a = BZ[o];
                a = MFMA16(wzf[o], zb, a);
                if (t == TT - 1) {
#pragma unroll
                    for (int q = 0; q < 4; ++q) pzlast[o][q] = fmaxf(a[q], 0.0f);
                }
                pzb[o] = cvt_relu(a);
            }

            // publish phi fragments for wave1
#pragma unroll
            for (int kt = 0; kt < 4; ++kt) {
                PHIB[kt * 64 + lane] = h2u(pxb[kt]);
                PHIB[(4 + kt) * 64 + lane] = h2u(pzb[kt]);
            }
            __syncthreads();   // B: wave1 may read phi(t); will write h(t) after this
        }

        // ================= regressor head on phi_z(T-1) (MFMA, wave0 only) =========
        half4 wf1t[4][4], wf2t[2][4], wf3t[2];
#pragma unroll
        for (int o = 0; o < 4; ++o)
#pragma unroll
            for (int kt = 0; kt < 4; ++kt) wf1t[o][kt] = ldw(Wf1, 64, 64, 64, kt * 16, o * 16, lane);
#pragma unroll
        for (int o = 0; o < 2; ++o)
#pragma unroll
            for (int kt = 0; kt < 4; ++kt) wf2t[o][kt] = ldw(Wf2, 32, 64, 32, kt * 16, o * 16, lane);
        wf3t[0] = ldw(Wf3, 1, 32, 1, 0, 0, lane);
        wf3t[1] = ldw(Wf3, 1, 32, 1, 16, 0, lane);
        f32x4 FB1[4], FB2[2];
#pragma unroll
        for (int o = 0; o < 4; ++o) FB1[o] = ldb4(bf1, o, lgr);
#pragma unroll
        for (int o = 0; o < 2; ++o) FB2[o] = ldb4(bf2, o, lgr);

        half4 o1b[4];
#pragma unroll
        for (int o = 0; o < 4; ++o) {
            f32x4 a = FB1[o];
#pragma unroll
            for (int kt = 0; kt < 4; ++kt) a = MFMA16(wf1t[o][kt], pzb[kt], a);
            o1b[o] = cvt_relu(a);
        }
        half4 o2b[2];
#pragma unroll
        for (int o = 0; o < 2; ++o) {
            f32x4 a = FB2[o];
#pragma unroll
            for (int kt = 0; kt < 4; ++kt) a = MFMA16(wf2t[o][kt], o1b[kt], a);
            o2b[o] = cvt_relu(a);
        }
        float b3 = bf3[0];
        f32x4 p = (f32x4){b3, b3, b3, b3};
        p = MFMA16(wf3t[0], o2b[0], p);
        p = MFMA16(wf3t[1], o2b[1], p);
        if (lgr == 0) out[r0 + lcol] = p[0];

        // phi_z output (f32, pre-cast accumulator values)
        float* po = out + BB + (size_t)(r0 + lcol) * 64;
#pragma unroll
        for (int o = 0; o < 4; ++o)
            *reinterpret_cast<f32x4*>(po + o * 16 + lgr * 4) = pzlast[o];

    } else {
        // ================= wave 1: GRU (gi, gh, gate update, h state) ==============
        half4 wih[12][8], whh[12][4];
#pragma unroll
        for (int ot = 0; ot < 12; ++ot) {
#pragma unroll
            for (int kt = 0; kt < 8; ++kt) wih[ot][kt] = ldw(Wih, 192, 128, 192, kt * 16, ot * 16, lane);
#pragma unroll
            for (int kt = 0; kt < 4; ++kt) whh[ot][kt] = ldw(Whh, 192, 64, 192, kt * 16, ot * 16, lane);
        }
        f32x4 hD[4];
        half4 hb[4];
        half4 hz;
#pragma unroll
        for (int j = 0; j < 4; ++j) hz[j] = (_Float16)0.0f;
#pragma unroll
        for (int o = 0; o < 4; ++o) {
            hD[o] = (f32x4){0.f, 0.f, 0.f, 0.f};
            hb[o] = hz;
            HBUF[o * 64 + lane] = h2u(hb[o]);
        }
        __syncthreads();   // pre-loop: h(-1)=0 published

#pragma unroll 1
        for (int t = 0; t < TT; ++t) {
            // gh = Whh^T @ hT(t-1): overlaps wave0's s1/s2
            f32x4 ga[12];
#pragma unroll
            for (int ot = 0; ot < 12; ++ot) {
                f32x4 a = (f32x4){0.f, 0.f, 0.f, 0.f};
#pragma unroll
                for (int kt = 0; kt < 4; ++kt) a = MFMA16(whh[ot][kt], hb[kt], a);
                ga[ot] = a;
            }
            __syncthreads();   // A
            __syncthreads();   // B: phi(t) ready

            half4 pb[8];
#pragma unroll
            for (int i = 0; i < 8; ++i) pb[i] = u2h(PHIB[i * 64 + lane]);

            // gi for r,z gates accumulates onto gh; n gate kept separate
#pragma unroll
            for (int ot = 0; ot < 8; ++ot) {
#pragma unroll
                for (int kt = 0; kt < 8; ++kt) ga[ot] = MFMA16(wih[ot][kt], pb[kt], ga[ot]);
            }
            f32x4 gin[4];
#pragma unroll
            for (int o = 0; o < 4; ++o) {
                f32x4 a = (f32x4){0.f, 0.f, 0.f, 0.f};
#pragma unroll
                for (int kt = 0; kt < 8; ++kt) a = MFMA16(wih[8 + o][kt], pb[kt], a);
                gin[o] = a;
            }
            // gate update (PyTorch order r,z,n; bias-free GRU)
#pragma unroll
            for (int o = 0; o < 4; ++o) {
#pragma unroll
                for (int q = 0; q < 4; ++q) {
                    float r = sigm(ga[o][q]);
                    float u = sigm(ga[4 + o][q]);
                    float n = tanh_fast(gin[o][q] + r * ga[8 + o][q]);
                    hD[o][q] = (1.0f - u) * n + u * hD[o][q];
                }
                hb[o] = cvt4(hD[o]);
                HBUF[o * 64 + lane] = h2u(hb[o]);
            }
        }
    }
}

extern "C" void kernel_launch(void* const* d_in, const int* in_sizes, int n_in,
                              void* d_out, int out_size, void* d_ws, size_t ws_size,
                              hipStream_t stream) {
    (void)in_sizes; (void)n_in; (void)d_ws; (void)ws_size; (void)out_size;
    const float* src = (const float*)d_in[0];
    const float* eps = (const float*)d_in[1];
    const float* Wx1 = (const float*)d_in[2];
    const float* bx1 = (const float*)d_in[3];
    const float* Wx2 = (const float*)d_in[4];
    const float* bx2 = (const float*)d_in[5];
    const float* Wz  = (const float*)d_in[6];
    const float* bz  = (const float*)d_in[7];
    const float* We1 = (const float*)d_in[8];
    const float* be1 = (const float*)d_in[9];
    const float* We2 = (const float*)d_in[10];
    const float* be2 = (const float*)d_in[11];
    const float* Wem = (const float*)d_in[12];
    const float* bem = (const float*)d_in[13];
    const float* Wes = (const float*)d_in[14];
    const float* bes = (const float*)d_in[15];
    const float* Wih = (const float*)d_in[16];
    const float* Whh = (const float*)d_in[17];
    const float* Wf1 = (const float*)d_in[18];
    const float* bf1 = (const float*)d_in[19];
    const float* Wf2 = (const float*)d_in[20];
    const float* bf2 = (const float*)d_in[21];
    const float* Wf3 = (const float*)d_in[22];
    const float* bf3 = (const float*)d_in[23];
    float* out = (float*)d_out;

    hipLaunchKernelGGL(vrnn_kernel, dim3(BB / 16), dim3(128), 0, stream,
                       src, eps, Wx1, bx1, Wx2, bx2, Wz, bz, We1, be1, We2, be2,
                       Wem, bem, Wes, bes, Wih, Whh, Wf1, bf1, Wf2, bf2, Wf3, bf3, out);
}

// Round 4
// 1808.445 us; speedup vs baseline: 1.2727x; 1.2727x over previous
//
#include <hip/hip_runtime.h>

#define TT 512
#define BB 1024
#define XD 24
#define ZD 16

typedef __attribute__((ext_vector_type(4))) _Float16 half4;
typedef __attribute__((ext_vector_type(4))) float f32x4;

__device__ __forceinline__ f32x4 MFMA16(half4 a, half4 b, f32x4 c) {
#if defined(__HIP_DEVICE_COMPILE__)
    return __builtin_amdgcn_mfma_f32_16x16x16f16(a, b, c, 0, 0, 0);
#else
    return c;   // host pass only needs to parse
#endif
}

__device__ __forceinline__ f32x4 Z4() { return (f32x4){0.f, 0.f, 0.f, 0.f}; }

__device__ __forceinline__ float sigm(float x) { return 1.0f / (1.0f + __expf(-x)); }

// tanh via 1 - 2/(1+e^{2x}); saturates correctly through inf/rcp, no clamp needed
__device__ __forceinline__ float tanh_fast(float x) {
    return 1.0f - 2.0f / (1.0f + __expf(2.0f * x));
}

__device__ __forceinline__ float softplus_f(float x) {
    return fmaxf(x, 0.0f) + log1pf(__expf(-fabsf(x)));
}

// A-fragment of W^T (16 out-feats x 16 k) for 16x16x16 f16 MFMA.
// Lane l holds W[k0+(l>>4)*4+j][o0+(l&15)], zero-padded outside Kreal/Nreal.
__device__ __forceinline__ half4 ldw(const float* W, int N, int Kreal, int Nreal,
                                     int k0, int o0, int lane) {
    int col = o0 + (lane & 15);
    int kb = k0 + ((lane >> 4) << 2);
    half4 r;
#pragma unroll
    for (int j = 0; j < 4; ++j) {
        int k = kb + j;
        float v = (k < Kreal && col < Nreal) ? W[(size_t)k * N + col] : 0.0f;
        r[j] = (_Float16)v;
    }
    return r;
}

__device__ __forceinline__ half4 cvt_relu(f32x4 a) {
    half4 r;
#pragma unroll
    for (int q = 0; q < 4; ++q) r[q] = (_Float16)fmaxf(a[q], 0.0f);
    return r;
}

__device__ __forceinline__ half4 cvt4(f32x4 a) {
    half4 r;
#pragma unroll
    for (int q = 0; q < 4; ++q) r[q] = (_Float16)a[q];
    return r;
}

__device__ __forceinline__ f32x4 ldb4(const float* b, int o, int lgr) {
    return *reinterpret_cast<const f32x4*>(b + o * 16 + lgr * 4);
}

__device__ __forceinline__ unsigned long long h2u(half4 h) {
    union { half4 h; unsigned long long u; } c; c.h = h; return c.u;
}
__device__ __forceinline__ half4 u2h(unsigned long long u) {
    union { half4 h; unsigned long long u; } c; c.u = u; return c.h;
}

__global__ __launch_bounds__(256, 1) void vrnn_kernel(
    const float* __restrict__ src, const float* __restrict__ eps,
    const float* __restrict__ Wx1, const float* __restrict__ bx1,
    const float* __restrict__ Wx2, const float* __restrict__ bx2,
    const float* __restrict__ Wz,  const float* __restrict__ bz,
    const float* __restrict__ We1, const float* __restrict__ be1,
    const float* __restrict__ We2, const float* __restrict__ be2,
    const float* __restrict__ Wem, const float* __restrict__ bem,
    const float* __restrict__ Wes, const float* __restrict__ bes,
    const float* __restrict__ Wih, const float* __restrict__ Whh,
    const float* __restrict__ Wf1, const float* __restrict__ bf1,
    const float* __restrict__ Wf2, const float* __restrict__ bf2,
    const float* __restrict__ Wf3, const float* __restrict__ bf3,
    float* __restrict__ out)
{
    __shared__ unsigned long long PXB[2][256];  // phi_x frags (double-buffered)
    __shared__ unsigned long long PZB[256];     // phi_z frags
    __shared__ unsigned long long HBUF[256];    // h frags
    __shared__ f32x4 RBUF[256];                 // r gate values (post-sigm)
    __shared__ f32x4 UBUF[256];                 // u gate values (post-sigm)

    const int tid = threadIdx.x;
    const int wid = tid >> 6;
    const int lane = tid & 63;
    const int lcol = lane & 15;
    const int lgr = lane >> 4;
    const int r0 = blockIdx.x * 16;

    if (wid == 0) {
        // ============ wave 0: s1/s2 one step ahead + u-gate (z in r,z,n order) ==========
        half4 wx1[4][2], wx2[4][4], wihU[4][8], whhU[4][4];
#pragma unroll
        for (int o = 0; o < 4; ++o) {
            wx1[o][0] = ldw(Wx1, 64, 24, 64, 0, o * 16, lane);
            wx1[o][1] = ldw(Wx1, 64, 24, 64, 16, o * 16, lane);
#pragma unroll
            for (int kt = 0; kt < 4; ++kt) wx2[o][kt] = ldw(Wx2, 64, 64, 64, kt * 16, o * 16, lane);
#pragma unroll
            for (int kt = 0; kt < 8; ++kt) wihU[o][kt] = ldw(Wih, 192, 128, 192, kt * 16, 64 + o * 16, lane);
#pragma unroll
            for (int kt = 0; kt < 4; ++kt) whhU[o][kt] = ldw(Whh, 192, 64, 192, kt * 16, 64 + o * 16, lane);
        }
        f32x4 B1[4], B2[4];
#pragma unroll
        for (int o = 0; o < 4; ++o) { B1[o] = ldb4(bx1, o, lgr); B2[o] = ldb4(bx2, o, lgr); }

        const float* xb_ = src + (size_t)(r0 + lcol) * TT * XD;
        f32x4 fx0 = *reinterpret_cast<const f32x4*>(xb_ + lgr * 4);
        f32x4 fx1 = Z4();
        if (lgr < 2) fx1 = *reinterpret_cast<const f32x4*>(xb_ + 16 + lgr * 4);

        // prologue: phi_x(0) -> PXB[0]; prefetch x(1)
        {
            half4 x0 = cvt4(fx0), x1 = cvt4(fx1);
            half4 axb[4], pxn[4];
#pragma unroll
            for (int o = 0; o < 4; ++o)
                axb[o] = cvt_relu(MFMA16(wx1[o][1], x1, MFMA16(wx1[o][0], x0, B1[o])));
#pragma unroll
            for (int o = 0; o < 4; ++o) {
                f32x4 a = B2[o];
#pragma unroll
                for (int kt = 0; kt < 4; ++kt) a = MFMA16(wx2[o][kt], axb[kt], a);
                pxn[o] = cvt_relu(a);
            }
#pragma unroll
            for (int kt = 0; kt < 4; ++kt) PXB[0][kt * 64 + lane] = h2u(pxn[kt]);
        }
        fx0 = *reinterpret_cast<const f32x4*>(xb_ + XD + lgr * 4);
        fx1 = Z4();
        if (lgr < 2) fx1 = *reinterpret_cast<const f32x4*>(xb_ + XD + 16 + lgr * 4);
        __syncthreads();

#pragma unroll 1
        for (int t = 0; t < TT; ++t) {
            // ph1: gh_u + phi_x(t+1)
            half4 hb[4];
#pragma unroll
            for (int kt = 0; kt < 4; ++kt) hb[kt] = u2h(HBUF[kt * 64 + lane]);
            f32x4 ga[4];
#pragma unroll
            for (int o = 0; o < 4; ++o) {
                f32x4 a = MFMA16(whhU[o][1], hb[1], MFMA16(whhU[o][0], hb[0], Z4()));
                f32x4 b = MFMA16(whhU[o][3], hb[3], MFMA16(whhU[o][2], hb[2], Z4()));
                ga[o] = a + b;
            }
            if (t + 1 < TT) {
                half4 x0 = cvt4(fx0), x1 = cvt4(fx1);
                half4 axb[4], pxn[4];
#pragma unroll
                for (int o = 0; o < 4; ++o)
                    axb[o] = cvt_relu(MFMA16(wx1[o][1], x1, MFMA16(wx1[o][0], x0, B1[o])));
#pragma unroll
                for (int o = 0; o < 4; ++o) {
                    f32x4 a = B2[o];
#pragma unroll
                    for (int kt = 0; kt < 4; ++kt) a = MFMA16(wx2[o][kt], axb[kt], a);
                    pxn[o] = cvt_relu(a);
                }
#pragma unroll
                for (int kt = 0; kt < 4; ++kt) PXB[(t + 1) & 1][kt * 64 + lane] = h2u(pxn[kt]);
                if (t + 2 < TT) {
                    fx0 = *reinterpret_cast<const f32x4*>(xb_ + (size_t)(t + 2) * XD + lgr * 4);
                    fx1 = Z4();
                    if (lgr < 2) fx1 = *reinterpret_cast<const f32x4*>(xb_ + (size_t)(t + 2) * XD + 16 + lgr * 4);
                }
            }
            __syncthreads();   // B: phi_z(t) published by w1
            // ph2: gi_u, u = sigm, publish
            half4 pb[8];
#pragma unroll
            for (int kt = 0; kt < 4; ++kt) pb[kt] = u2h(PXB[t & 1][kt * 64 + lane]);
#pragma unroll
            for (int kt = 0; kt < 4; ++kt) pb[4 + kt] = u2h(PZB[kt * 64 + lane]);
#pragma unroll
            for (int o = 0; o < 4; ++o) {
                f32x4 a = ga[o];
#pragma unroll
                for (int kt = 0; kt < 4; ++kt) a = MFMA16(wihU[o][kt], pb[kt], a);
                f32x4 b = Z4();
#pragma unroll
                for (int kt = 0; kt < 4; ++kt) b = MFMA16(wihU[o][4 + kt], pb[4 + kt], b);
                f32x4 s = a + b;
                f32x4 uv;
#pragma unroll
                for (int q = 0; q < 4; ++q) uv[q] = sigm(s[q]);
                UBUF[o * 64 + lane] = uv;
            }
            __syncthreads();   // C
            __syncthreads();   // D
        }

    } else if (wid == 1) {
        // ============ wave 1: enc chain s3..s6 + z + phi_z + head =======================
        half4 we1[4][8], we2[4][4], wem[4], wes[4], wzf[4];
#pragma unroll
        for (int o = 0; o < 4; ++o) {
#pragma unroll
            for (int kt = 0; kt < 8; ++kt) we1[o][kt] = ldw(We1, 64, 128, 64, kt * 16, o * 16, lane);
#pragma unroll
            for (int kt = 0; kt < 4; ++kt) we2[o][kt] = ldw(We2, 64, 64, 64, kt * 16, o * 16, lane);
            wzf[o] = ldw(Wz, 64, 16, 64, 0, o * 16, lane);
        }
#pragma unroll
        for (int kt = 0; kt < 4; ++kt) {
            wem[kt] = ldw(Wem, 16, 64, 16, kt * 16, 0, lane);
            wes[kt] = ldw(Wes, 16, 64, 16, kt * 16, 0, lane);
        }
        f32x4 BE1[4], BE2[4], BZ[4];
#pragma unroll
        for (int o = 0; o < 4; ++o) {
            BE1[o] = ldb4(be1, o, lgr);
            BE2[o] = ldb4(be2, o, lgr);
            BZ[o] = ldb4(bz, o, lgr);
        }
        f32x4 BM = ldb4(bem, 0, lgr), BS = ldb4(bes, 0, lgr);

        const float* eb_ = eps + (size_t)(r0 + lcol) * TT * ZD;
        f32x4 fe = *reinterpret_cast<const f32x4*>(eb_ + lgr * 4);

        f32x4 pzlast[4];
        half4 pzb[4];
        __syncthreads();

#pragma unroll 1
        for (int t = 0; t < TT; ++t) {
            // ph1: the serial chain
            half4 hb[4], pxb[4];
#pragma unroll
            for (int kt = 0; kt < 4; ++kt) hb[kt] = u2h(HBUF[kt * 64 + lane]);
#pragma unroll
            for (int kt = 0; kt < 4; ++kt) pxb[kt] = u2h(PXB[t & 1][kt * 64 + lane]);

            half4 a1b[4], enb[4];
#pragma unroll
            for (int o = 0; o < 4; ++o) {
                f32x4 a = BE1[o];
#pragma unroll
                for (int kt = 0; kt < 4; ++kt) a = MFMA16(we1[o][kt], pxb[kt], a);
                f32x4 b = Z4();
#pragma unroll
                for (int kt = 0; kt < 4; ++kt) b = MFMA16(we1[o][4 + kt], hb[kt], b);
                a1b[o] = cvt_relu(a + b);
            }
#pragma unroll
            for (int o = 0; o < 4; ++o) {
                f32x4 a = MFMA16(we2[o][1], a1b[1], MFMA16(we2[o][0], a1b[0], BE2[o]));
                f32x4 b = MFMA16(we2[o][3], a1b[3], MFMA16(we2[o][2], a1b[2], Z4()));
                enb[o] = cvt_relu(a + b);
            }
            f32x4 am = MFMA16(wem[1], enb[1], MFMA16(wem[0], enb[0], BM));
            f32x4 am2 = MFMA16(wem[3], enb[3], MFMA16(wem[2], enb[2], Z4()));
            f32x4 as_ = MFMA16(wes[1], enb[1], MFMA16(wes[0], enb[0], BS));
            f32x4 as2 = MFMA16(wes[3], enb[3], MFMA16(wes[2], enb[2], Z4()));
            f32x4 eC = fe;
            if (t + 1 < TT) fe = *reinterpret_cast<const f32x4*>(eb_ + (size_t)(t + 1) * ZD + lgr * 4);
            f32x4 zD;
#pragma unroll
            for (int q = 0; q < 4; ++q)
                zD[q] = eC[q] * softplus_f(as_[q] + as2[q]) + (am[q] + am2[q]);
            half4 zb = cvt4(zD);
#pragma unroll
            for (int o = 0; o < 4; ++o) {
                f32x4 a = MFMA16(wzf[o], zb, BZ[o]);
                if (t == TT - 1) {
#pragma unroll
                    for (int q = 0; q < 4; ++q) pzlast[o][q] = fmaxf(a[q], 0.0f);
                }
                pzb[o] = cvt_relu(a);
                PZB[o * 64 + lane] = h2u(pzb[o]);
            }
            __syncthreads();   // B
            __syncthreads();   // C
            __syncthreads();   // D
        }

        // head on phi_z(T-1)
        half4 wf1t[4][4], wf2t[2][4], wf3t[2];
#pragma unroll
        for (int o = 0; o < 4; ++o)
#pragma unroll
            for (int kt = 0; kt < 4; ++kt) wf1t[o][kt] = ldw(Wf1, 64, 64, 64, kt * 16, o * 16, lane);
#pragma unroll
        for (int o = 0; o < 2; ++o)
#pragma unroll
            for (int kt = 0; kt < 4; ++kt) wf2t[o][kt] = ldw(Wf2, 32, 64, 32, kt * 16, o * 16, lane);
        wf3t[0] = ldw(Wf3, 1, 32, 1, 0, 0, lane);
        wf3t[1] = ldw(Wf3, 1, 32, 1, 16, 0, lane);
        f32x4 FB1[4], FB2[2];
#pragma unroll
        for (int o = 0; o < 4; ++o) FB1[o] = ldb4(bf1, o, lgr);
#pragma unroll
        for (int o = 0; o < 2; ++o) FB2[o] = ldb4(bf2, o, lgr);

        half4 o1b[4];
#pragma unroll
        for (int o = 0; o < 4; ++o) {
            f32x4 a = FB1[o];
#pragma unroll
            for (int kt = 0; kt < 4; ++kt) a = MFMA16(wf1t[o][kt], pzb[kt], a);
            o1b[o] = cvt_relu(a);
        }
        half4 o2b[2];
#pragma unroll
        for (int o = 0; o < 2; ++o) {
            f32x4 a = FB2[o];
#pragma unroll
            for (int kt = 0; kt < 4; ++kt) a = MFMA16(wf2t[o][kt], o1b[kt], a);
            o2b[o] = cvt_relu(a);
        }
        float b3 = bf3[0];
        f32x4 p = (f32x4){b3, b3, b3, b3};
        p = MFMA16(wf3t[0], o2b[0], p);
        p = MFMA16(wf3t[1], o2b[1], p);
        if (lgr == 0) out[r0 + lcol] = p[0];

        float* po = out + BB + (size_t)(r0 + lcol) * 64;
#pragma unroll
        for (int o = 0; o < 4; ++o)
            *reinterpret_cast<f32x4*>(po + o * 16 + lgr * 4) = pzlast[o];

    } else if (wid == 2) {
        // ============ wave 2: r-gate ====================================================
        half4 wihR[4][8], whhR[4][4];
#pragma unroll
        for (int o = 0; o < 4; ++o) {
#pragma unroll
            for (int kt = 0; kt < 8; ++kt) wihR[o][kt] = ldw(Wih, 192, 128, 192, kt * 16, o * 16, lane);
#pragma unroll
            for (int kt = 0; kt < 4; ++kt) whhR[o][kt] = ldw(Whh, 192, 64, 192, kt * 16, o * 16, lane);
        }
        __syncthreads();

#pragma unroll 1
        for (int t = 0; t < TT; ++t) {
            half4 hb[4];
#pragma unroll
            for (int kt = 0; kt < 4; ++kt) hb[kt] = u2h(HBUF[kt * 64 + lane]);
            f32x4 ga[4];
#pragma unroll
            for (int o = 0; o < 4; ++o) {
                f32x4 a = MFMA16(whhR[o][1], hb[1], MFMA16(whhR[o][0], hb[0], Z4()));
                f32x4 b = MFMA16(whhR[o][3], hb[3], MFMA16(whhR[o][2], hb[2], Z4()));
                ga[o] = a + b;
            }
            __syncthreads();   // B
            half4 pb[8];
#pragma unroll
            for (int kt = 0; kt < 4; ++kt) pb[kt] = u2h(PXB[t & 1][kt * 64 + lane]);
#pragma unroll
            for (int kt = 0; kt < 4; ++kt) pb[4 + kt] = u2h(PZB[kt * 64 + lane]);
#pragma unroll
            for (int o = 0; o < 4; ++o) {
                f32x4 a = ga[o];
#pragma unroll
                for (int kt = 0; kt < 4; ++kt) a = MFMA16(wihR[o][kt], pb[kt], a);
                f32x4 b = Z4();
#pragma unroll
                for (int kt = 0; kt < 4; ++kt) b = MFMA16(wihR[o][4 + kt], pb[4 + kt], b);
                f32x4 s = a + b;
                f32x4 rv;
#pragma unroll
                for (int q = 0; q < 4; ++q) rv[q] = sigm(s[q]);
                RBUF[o * 64 + lane] = rv;
            }
            __syncthreads();   // C
            __syncthreads();   // D
        }

    } else {
        // ============ wave 3: n-gate + h owner ==========================================
        half4 wihN[4][8], whhN[4][4];
#pragma unroll
        for (int o = 0; o < 4; ++o) {
#pragma unroll
            for (int kt = 0; kt < 8; ++kt) wihN[o][kt] = ldw(Wih, 192, 128, 192, kt * 16, 128 + o * 16, lane);
#pragma unroll
            for (int kt = 0; kt < 4; ++kt) whhN[o][kt] = ldw(Whh, 192, 64, 192, kt * 16, 128 + o * 16, lane);
        }
        f32x4 hD[4];
        half4 hb[4];
        half4 hz;
#pragma unroll
        for (int j = 0; j < 4; ++j) hz[j] = (_Float16)0.0f;
#pragma unroll
        for (int o = 0; o < 4; ++o) {
            hD[o] = Z4();
            hb[o] = hz;
            HBUF[o * 64 + lane] = h2u(hb[o]);
        }
        __syncthreads();

#pragma unroll 1
        for (int t = 0; t < TT; ++t) {
            // ph1: ghn from own h regs
            f32x4 gh[4];
#pragma unroll
            for (int o = 0; o < 4; ++o) {
                f32x4 a = MFMA16(whhN[o][1], hb[1], MFMA16(whhN[o][0], hb[0], Z4()));
                f32x4 b = MFMA16(whhN[o][3], hb[3], MFMA16(whhN[o][2], hb[2], Z4()));
                gh[o] = a + b;
            }
            __syncthreads();   // B
            half4 pb[8];
#pragma unroll
            for (int kt = 0; kt < 4; ++kt) pb[kt] = u2h(PXB[t & 1][kt * 64 + lane]);
#pragma unroll
            for (int kt = 0; kt < 4; ++kt) pb[4 + kt] = u2h(PZB[kt * 64 + lane]);
            f32x4 gi[4];
#pragma unroll
            for (int o = 0; o < 4; ++o) {
                f32x4 a = Z4();
#pragma unroll
                for (int kt = 0; kt < 4; ++kt) a = MFMA16(wihN[o][kt], pb[kt], a);
                f32x4 b = Z4();
#pragma unroll
                for (int kt = 0; kt < 4; ++kt) b = MFMA16(wihN[o][4 + kt], pb[4 + kt], b);
                gi[o] = a + b;
            }
            __syncthreads();   // C
            // ph3: gates + h update + publish
#pragma unroll
            for (int o = 0; o < 4; ++o) {
                f32x4 rr = RBUF[o * 64 + lane];
                f32x4 uu = UBUF[o * 64 + lane];
#pragma unroll
                for (int q = 0; q < 4; ++q) {
                    float n = tanh_fast(gi[o][q] + rr[q] * gh[o][q]);
                    hD[o][q] = (1.0f - uu[q]) * n + uu[q] * hD[o][q];
                }
                hb[o] = cvt4(hD[o]);
                HBUF[o * 64 + lane] = h2u(hb[o]);
            }
            __syncthreads();   // D
        }
    }
}

extern "C" void kernel_launch(void* const* d_in, const int* in_sizes, int n_in,
                              void* d_out, int out_size, void* d_ws, size_t ws_size,
                              hipStream_t stream) {
    (void)in_sizes; (void)n_in; (void)d_ws; (void)ws_size; (void)out_size;
    const float* src = (const float*)d_in[0];
    const float* eps = (const float*)d_in[1];
    const float* Wx1 = (const float*)d_in[2];
    const float* bx1 = (const float*)d_in[3];
    const float* Wx2 = (const float*)d_in[4];
    const float* bx2 = (const float*)d_in[5];
    const float* Wz  = (const float*)d_in[6];
    const float* bz  = (const float*)d_in[7];
    const float* We1 = (const float*)d_in[8];
    const float* be1 = (const float*)d_in[9];
    const float* We2 = (const float*)d_in[10];
    const float* be2 = (const float*)d_in[11];
    const float* Wem = (const float*)d_in[12];
    const float* bem = (const float*)d_in[13];
    const float* Wes = (const float*)d_in[14];
    const float* bes = (const float*)d_in[15];
    const float* Wih = (const float*)d_in[16];
    const float* Whh = (const float*)d_in[17];
    const float* Wf1 = (const float*)d_in[18];
    const float* bf1 = (const float*)d_in[19];
    const float* Wf2 = (const float*)d_in[20];
    const float* bf2 = (const float*)d_in[21];
    const float* Wf3 = (const float*)d_in[22];
    const float* bf3 = (const float*)d_in[23];
    float* out = (float*)d_out;

    hipLaunchKernelGGL(vrnn_kernel, dim3(BB / 16), dim3(256), 0, stream,
                       src, eps, Wx1, bx1, Wx2, bx2, Wz, bz, We1, be1, We2, be2,
                       Wem, bem, Wes, bes, Wih, Whh, Wf1, bf1, Wf2, bf2, Wf3, bf3, out);
}